// Round 13
// baseline (827.167 us; speedup 1.0000x reference)
//
#include <hip/hip_runtime.h>
#include <hip/hip_fp16.h>
#include <hip/hip_cooperative_groups.h>

namespace cg = cooperative_groups;

#define BN_EPS 1e-5f
#define CHUNK 4096            // edges per bucketing chunk
#define BBITS 7               // 128 nodes per bucket
#define PREP_G 512            // cooperative prep grid (256 thr; low VGPR/LDS -> co-resident)

typedef _Float16 half8 __attribute__((ext_vector_type(8)));
typedef float f32x4 __attribute__((ext_vector_type(4)));

__device__ __forceinline__ float4 f4zero() { return make_float4(0.f, 0.f, 0.f, 0.f); }

// ---------------- fused cooperative prep: 8 phases, 7 grid syncs ----------------

struct PrepArgs {
    const float* W1; const float* W2; const float* W3;
    _Float16* pW;
    const int* src; const int* dst;
    int* tableT;        // [nbuck][nA] -> exclusive scanned
    int* parts;         // segment partials
    int2* bed;          // bucket-grouped COO
    int* brank;
    int* counts;
    float* dinv;
    int* localOff;
    int* btot;
    int* bucketBase;
    int* offs;
    int* er;
    unsigned int* bufAzero;   // 256 B pad row of bufA
    int nA, nbuck, tlen, nseg, n, e;
};

__global__ __launch_bounds__(256) void k_prep(PrepArgs P) {
    cg::grid_group grid = cg::this_grid();
    __shared__ int smem[1280];
    int bid = blockIdx.x, tid = threadIdx.x;
    int G = gridDim.x;

    // ---- P0: packW (grid-stride) + bucket histogram (grid-stride over chunks) ----
    for (int t = bid * 256 + tid; t < 6144; t += G * 256) {
        int wi = t >> 11;
        int tt = t & 2047;
        const float* W = (wi == 0) ? P.W1 : ((wi == 1) ? P.W2 : P.W3);
        int kc = tt >> 9;
        int rem = tt & 511;
        int ct = rem >> 6;
        int lane = rem & 63;
        int q = lane >> 4;
        int col = ct * 16 + (lane & 15);
        half8 hh;
#pragma unroll
        for (int j = 0; j < 8; ++j)
            hh[j] = (_Float16)W[(kc * 32 + q * 8 + j) * 128 + col];
        *(half8*)(P.pW + (size_t)t * 8) = hh;
    }
    for (int c = bid; c < P.nA; c += G) {
        for (int k = tid; k < 1024; k += 256) smem[k] = 0;
        __syncthreads();
        int base = c * CHUNK;
        if (base + CHUNK <= P.e) {
            const int4* d4 = (const int4*)(P.dst + base);
#pragma unroll
            for (int t = 0; t < CHUNK / 1024; ++t) {
                int4 d = d4[t * 256 + tid];
                atomicAdd(&smem[d.x >> BBITS], 1);
                atomicAdd(&smem[d.y >> BBITS], 1);
                atomicAdd(&smem[d.z >> BBITS], 1);
                atomicAdd(&smem[d.w >> BBITS], 1);
            }
        } else {
            for (int i = base + tid; i < P.e; i += 256)
                atomicAdd(&smem[P.dst[i] >> BBITS], 1);
        }
        __syncthreads();
        for (int k = tid; k < P.nbuck; k += 256)
            P.tableT[(size_t)k * P.nA + c] = smem[k];
        __syncthreads();
    }
    grid.sync();

    // ---- P1: segment scan of tableT (1024-elem segments, 256 thr x 4) ----
    for (int s = bid; s < P.nseg; s += G) {
        int base = s * 1024;
        int v[4], loc[4], tsum = 0;
#pragma unroll
        for (int j = 0; j < 4; ++j) {
            int idx = base + tid * 4 + j;
            v[j] = (idx < P.tlen) ? P.tableT[idx] : 0;
            loc[j] = tsum;
            tsum += v[j];
        }
        int x = tsum;
        smem[tid] = x;
        __syncthreads();
        for (int d = 1; d < 256; d <<= 1) {
            int y = (tid >= d) ? smem[tid - d] : 0;
            __syncthreads();
            x += y;
            smem[tid] = x;
            __syncthreads();
        }
        int excl = x - tsum;
#pragma unroll
        for (int j = 0; j < 4; ++j) {
            int idx = base + tid * 4 + j;
            if (idx < P.tlen) P.tableT[idx] = excl + loc[j];
        }
        if (tid == 255) P.parts[s] = excl + tsum;
        __syncthreads();
    }
    grid.sync();

    // ---- P2: single-block exclusive scan of segment partials ----
    if (bid == 0) {
        int v[4], loc[4], tsum = 0;
#pragma unroll
        for (int j = 0; j < 4; ++j) {
            int idx = tid * 4 + j;
            v[j] = (idx < P.nseg) ? P.parts[idx] : 0;
            loc[j] = tsum;
            tsum += v[j];
        }
        int x = tsum;
        smem[tid] = x;
        __syncthreads();
        for (int d = 1; d < 256; d <<= 1) {
            int y = (tid >= d) ? smem[tid - d] : 0;
            __syncthreads();
            x += y;
            smem[tid] = x;
            __syncthreads();
        }
        int excl = x - tsum;
#pragma unroll
        for (int j = 0; j < 4; ++j) {
            int idx = tid * 4 + j;
            if (idx < P.nseg) P.parts[idx] = excl + loc[j];
        }
    }
    grid.sync();

    // ---- P3: add segment bases back ----
    for (int i = bid * 256 + tid; i < P.tlen; i += G * 256)
        P.tableT[i] += P.parts[i >> 10];
    grid.sync();

    // ---- P4: bucket-grouped COO scatter (LDS cursors per chunk) ----
    for (int c = bid; c < P.nA; c += G) {
        for (int k = tid; k < P.nbuck; k += 256)
            smem[k] = P.tableT[(size_t)k * P.nA + c];
        __syncthreads();
        int base = c * CHUNK;
        if (base + CHUNK <= P.e) {
            const int4* s4 = (const int4*)(P.src + base);
            const int4* d4 = (const int4*)(P.dst + base);
#pragma unroll
            for (int t = 0; t < CHUNK / 1024; ++t) {
                int4 s = s4[t * 256 + tid];
                int4 d = d4[t * 256 + tid];
                int p0 = atomicAdd(&smem[d.x >> BBITS], 1); P.bed[p0] = make_int2(s.x, d.x);
                int p1 = atomicAdd(&smem[d.y >> BBITS], 1); P.bed[p1] = make_int2(s.y, d.y);
                int p2 = atomicAdd(&smem[d.z >> BBITS], 1); P.bed[p2] = make_int2(s.z, d.z);
                int p3 = atomicAdd(&smem[d.w >> BBITS], 1); P.bed[p3] = make_int2(s.w, d.w);
            }
        } else {
            for (int i = base + tid; i < P.e; i += 256) {
                int d = P.dst[i];
                int p = atomicAdd(&smem[d >> BBITS], 1);
                P.bed[p] = make_int2(P.src[i], d);
            }
        }
        __syncthreads();
    }
    grid.sync();

    // ---- P5: per-bucket rank + counts + dinv + padded local offsets + btot ----
    for (int b = bid; b < P.nbuck; b += G) {
        int* lcnt = smem;          // [128]
        int* lscan = smem + 128;   // [128]
        if (tid < 128) lcnt[tid] = 0;
        __syncthreads();
        int start = P.tableT[(size_t)b * P.nA];
        int end = (b + 1 < P.nbuck) ? P.tableT[(size_t)(b + 1) * P.nA] : P.e;
        for (int i = start + tid; i < end; i += 256) {
            int2 q = P.bed[i];
            P.brank[i] = atomicAdd(&lcnt[q.y & 127], 1);
        }
        __syncthreads();
        int padded = 0;
        if (tid < 128) {
            padded = (lcnt[tid] + 7) & ~7;
            lscan[tid] = padded;
        }
        __syncthreads();
        for (int d = 1; d < 128; d <<= 1) {
            int y = (tid < 128 && tid >= d) ? lscan[tid - d] : 0;
            __syncthreads();
            if (tid < 128) lscan[tid] += y;
            __syncthreads();
        }
        if (tid < 128) {
            int node = (b << BBITS) + tid;
            if (node < P.n) {
                int c = lcnt[tid];
                P.counts[node] = c;
                P.dinv[node] = rsqrtf((float)(c + 1));
                P.localOff[node] = lscan[tid] - padded;
            }
            if (tid == 127) P.btot[b] = lscan[127];
        }
        __syncthreads();
    }
    grid.sync();

    // ---- P6: single-block exclusive scan of btot -> bucketBase (+ total) ----
    if (bid == 0) {
        int v[4], loc[4], tsum = 0;
#pragma unroll
        for (int j = 0; j < 4; ++j) {
            int idx = tid * 4 + j;
            v[j] = (idx < P.nbuck) ? P.btot[idx] : 0;
            loc[j] = tsum;
            tsum += v[j];
        }
        int x = tsum;
        smem[tid] = x;
        __syncthreads();
        for (int d = 1; d < 256; d <<= 1) {
            int y = (tid >= d) ? smem[tid - d] : 0;
            __syncthreads();
            x += y;
            smem[tid] = x;
            __syncthreads();
        }
        int excl = x - tsum;
#pragma unroll
        for (int j = 0; j < 4; ++j) {
            int idx = tid * 4 + j;
            if (idx < P.nbuck) P.bucketBase[idx] = excl + loc[j];
            if (idx == P.nbuck - 1) P.bucketBase[P.nbuck] = excl + loc[j] + v[j];
        }
    }
    grid.sync();

    // ---- P7: finalize: offs + pad-fill + zero-row, then place edges ----
    if (bid == 0 && tid < 64) P.bufAzero[tid] = 0u;
    for (int node = bid * 256 + tid; node < P.n; node += G * 256) {
        int c = P.counts[node];
        int o = P.bucketBase[node >> BBITS] + P.localOff[node];
        P.offs[node] = o;
        int pc = (c + 7) & ~7;
        for (int j = c; j < pc; ++j) P.er[o + j] = P.n;   // dummy zero-row index
    }
    if (bid == 0 && tid == 0) P.offs[P.n] = P.bucketBase[P.nbuck];
    int npair = (P.e + 1) / 2;
    for (int ip = bid * 256 + tid; ip < npair; ip += G * 256) {
        int i = ip * 2;
        if (i + 1 < P.e) {
            int4 q = *(const int4*)(P.bed + i);      // (s0,d0,s1,d1)
            int2 r = *(const int2*)(P.brank + i);
            P.er[P.bucketBase[q.y >> BBITS] + P.localOff[q.y] + r.x] = q.x;
            P.er[P.bucketBase[q.w >> BBITS] + P.localOff[q.w] + r.y] = q.z;
        } else {
            int2 q = P.bed[i];
            P.er[P.bucketBase[q.y >> BBITS] + P.localOff[q.y] + P.brank[i]] = q.x;
        }
    }
}

// ---------------- MFMA GEMM: C[n,128](f16, row-major) = (A @ W) * dinv[row] ----------------
// (R12-verified structure, unchanged)

template <bool AF32>
__global__ __launch_bounds__(256) void k_gemm_mfma(const void* __restrict__ Av,
                                                   const _Float16* __restrict__ pW,
                                                   const float* __restrict__ dinv,
                                                   uint4* __restrict__ C, int n) {
    __shared__ char smem[32768];
    uint4* sW = (uint4*)smem;
    int tid = threadIdx.x;

    {
        const uint4* gW = (const uint4*)pW;
#pragma unroll
        for (int i = 0; i < 8; ++i) sW[tid + 256 * i] = gW[tid + 256 * i];
    }
    __syncthreads();

    int wave = tid >> 6, lane = tid & 63;
    int quad = lane >> 4, l16 = lane & 15;
    int row0 = blockIdx.x * 64 + wave * 16;
    int arow = row0 + l16;
    int arowc = (arow < n) ? arow : (n - 1);

    half8 af[4];
    if (AF32) {
        const float* A = (const float*)Av + (size_t)arowc * 128 + quad * 8;
#pragma unroll
        for (int kc = 0; kc < 4; ++kc) {
            float4 lo = *(const float4*)(A + kc * 32);
            float4 hi = *(const float4*)(A + kc * 32 + 4);
            half8 h;
            h[0] = (_Float16)lo.x; h[1] = (_Float16)lo.y;
            h[2] = (_Float16)lo.z; h[3] = (_Float16)lo.w;
            h[4] = (_Float16)hi.x; h[5] = (_Float16)hi.y;
            h[6] = (_Float16)hi.z; h[7] = (_Float16)hi.w;
            af[kc] = h;
        }
    } else {
        const _Float16* A = (const _Float16*)Av + (size_t)arowc * 128 + quad * 8;
#pragma unroll
        for (int kc = 0; kc < 4; ++kc)
            af[kc] = *(const half8*)(A + kc * 32);
    }

    f32x4 acc[8];
#pragma unroll
    for (int ct = 0; ct < 8; ++ct) acc[ct] = (f32x4){0.f, 0.f, 0.f, 0.f};

#pragma unroll
    for (int kc = 0; kc < 4; ++kc) {
#pragma unroll
        for (int ct = 0; ct < 8; ++ct) {
            half8 bf = *(half8*)&sW[(kc * 8 + ct) * 64 + lane];
            acc[ct] = __builtin_amdgcn_mfma_f32_16x16x32_f16(af[kc], bf, acc[ct], 0, 0, 0);
        }
    }

    __syncthreads();

    _Float16* eb = (_Float16*)smem + wave * 16 * 136;   // 136 halfs = 272 B row stride
    float dv[4];
#pragma unroll
    for (int r = 0; r < 4; ++r) {
        int rr = row0 + quad * 4 + r;
        dv[r] = dinv[(rr < n) ? rr : (n - 1)];
    }
#pragma unroll
    for (int ct = 0; ct < 8; ++ct)
#pragma unroll
        for (int r = 0; r < 4; ++r)
            eb[(quad * 4 + r) * 136 + ct * 16 + l16] = (_Float16)(acc[ct][r] * dv[r]);

#pragma unroll
    for (int i = 0; i < 4; ++i) {
        int linear = i * 64 + lane;
        int r = linear >> 4, c = linear & 15;
        uint4 v = *(uint4*)((char*)eb + r * 272 + c * 16);
        int row = row0 + r;
        if (row < n) C[(size_t)row * 16 + c] = v;
    }
}

// ---------------- CSR aggregation + bias + ReLU + BN (+ optional classifier) ----------------
// (R12-verified structure, unchanged: 32 lanes/node, uint2 gathers, batch-8)

__device__ __forceinline__ void acc_row(float4& acc, uint2 q) {
    float2 f01 = __half22float2(*(__half2*)&q.x);
    float2 f23 = __half22float2(*(__half2*)&q.y);
    acc.x += f01.x; acc.y += f01.y; acc.z += f23.x; acc.w += f23.y;
}

template <bool FUSE_CLS>
__global__ __launch_bounds__(256) void k_aggregate(const uint2* __restrict__ Ah,
                                                   const int* __restrict__ offs,
                                                   const int* __restrict__ er,
                                                   const float* __restrict__ dinv,
                                                   const float* __restrict__ bias,
                                                   const float* __restrict__ g,
                                                   const float* __restrict__ be,
                                                   const float* __restrict__ rm,
                                                   const float* __restrict__ rv,
                                                   uint2* __restrict__ Hout,
                                                   const float* __restrict__ Wc,
                                                   const float* __restrict__ bc,
                                                   float* __restrict__ out, int n) {
    int lane = threadIdx.x & 31;
    int node = blockIdx.x * 8 + (threadIdx.x >> 5);
    if (node >= n) return;

    float4 acc = f4zero();
    acc_row(acc, Ah[(size_t)node * 32 + lane]);   // self loop (weight folds to dinv^2)

    int e0 = offs[node], e1 = offs[node + 1];
    for (int e = e0; e < e1; e += 8) {
        int4 ra = *(const int4*)(er + e);
        int4 rb = *(const int4*)(er + e + 4);
        uint2 v0 = Ah[(size_t)ra.x * 32 + lane];
        uint2 v1 = Ah[(size_t)ra.y * 32 + lane];
        uint2 v2 = Ah[(size_t)ra.z * 32 + lane];
        uint2 v3 = Ah[(size_t)ra.w * 32 + lane];
        uint2 v4 = Ah[(size_t)rb.x * 32 + lane];
        uint2 v5 = Ah[(size_t)rb.y * 32 + lane];
        uint2 v6 = Ah[(size_t)rb.z * 32 + lane];
        uint2 v7 = Ah[(size_t)rb.w * 32 + lane];
        acc_row(acc, v0); acc_row(acc, v1); acc_row(acc, v2); acc_row(acc, v3);
        acc_row(acc, v4); acc_row(acc, v5); acc_row(acc, v6); acc_row(acc, v7);
    }

    float di = dinv[node];
    acc.x *= di; acc.y *= di; acc.z *= di; acc.w *= di;

    float4 b4  = ((const float4*)bias)[lane];
    float4 g4  = ((const float4*)g)[lane];
    float4 be4 = ((const float4*)be)[lane];
    float4 rm4 = ((const float4*)rm)[lane];
    float4 rv4 = ((const float4*)rv)[lane];

    float4 o;
    float v;
    v = fmaxf(acc.x + b4.x, 0.f); o.x = (v - rm4.x) * rsqrtf(rv4.x + BN_EPS) * g4.x + be4.x;
    v = fmaxf(acc.y + b4.y, 0.f); o.y = (v - rm4.y) * rsqrtf(rv4.y + BN_EPS) * g4.y + be4.y;
    v = fmaxf(acc.z + b4.z, 0.f); o.z = (v - rm4.z) * rsqrtf(rv4.z + BN_EPS) * g4.z + be4.z;
    v = fmaxf(acc.w + b4.w, 0.f); o.w = (v - rm4.w) * rsqrtf(rv4.w + BN_EPS) * g4.w + be4.w;

    if (!FUSE_CLS) {
        __half2 p0 = __floats2half2_rn(o.x, o.y);
        __half2 p1 = __floats2half2_rn(o.z, o.w);
        uint2 u;
        u.x = *(unsigned int*)&p0;
        u.y = *(unsigned int*)&p1;
        Hout[(size_t)node * 32 + lane] = u;
    } else {
        const float4* Wv = (const float4*)Wc;
        float4 w01 = Wv[2 * lane];
        float4 w23 = Wv[2 * lane + 1];
        float p0 = o.x * w01.x + o.y * w01.z + o.z * w23.x + o.w * w23.z;
        float p1 = o.x * w01.y + o.y * w01.w + o.z * w23.y + o.w * w23.w;
#pragma unroll
        for (int d = 16; d >= 1; d >>= 1) {
            p0 += __shfl_down(p0, d, 32);
            p1 += __shfl_down(p1, d, 32);
        }
        if (lane == 0) {
            out[node * 2 + 0] = p0 + bc[0];
            out[node * 2 + 1] = p1 + bc[1];
        }
    }
}

// ---------------- launch ----------------

extern "C" void kernel_launch(void* const* d_in, const int* in_sizes, int n_in,
                              void* d_out, int out_size, void* d_ws, size_t ws_size,
                              hipStream_t stream) {
    const float* x   = (const float*)d_in[0];
    const int*   ei  = (const int*)d_in[1];
    const float* W1  = (const float*)d_in[2];
    const float* b1  = (const float*)d_in[3];
    const float* W2  = (const float*)d_in[4];
    const float* b2  = (const float*)d_in[5];
    const float* W3  = (const float*)d_in[6];
    const float* b3  = (const float*)d_in[7];
    const float* g1  = (const float*)d_in[8];
    const float* be1 = (const float*)d_in[9];
    const float* rm1 = (const float*)d_in[10];
    const float* rv1 = (const float*)d_in[11];
    const float* g2  = (const float*)d_in[12];
    const float* be2 = (const float*)d_in[13];
    const float* rm2 = (const float*)d_in[14];
    const float* rv2 = (const float*)d_in[15];
    const float* g3  = (const float*)d_in[16];
    const float* be3 = (const float*)d_in[17];
    const float* rm3 = (const float*)d_in[18];
    const float* rv3 = (const float*)d_in[19];
    const float* Wc  = (const float*)d_in[20];
    const float* bc  = (const float*)d_in[21];
    float* out = (float*)d_out;

    int n = in_sizes[0] / 128;
    int e = in_sizes[1] / 2;
    const int* src = ei;
    const int* dst = ei + e;

    char* ws = (char*)d_ws;
    size_t off = 0;
    auto alloc = [&](size_t bytes) -> char* {
        char* p = ws + off;
        off += (bytes + 255) & ~(size_t)255;
        return p;
    };
    int nA    = (e + CHUNK - 1) / CHUNK;
    int nbuck = (n + (1 << BBITS) - 1) >> BBITS;
    int tlen  = nbuck * nA;
    int nseg  = (tlen + 1023) / 1024;
    int erCap = e + 8 * n;

    char*      bufA     = (char*) alloc((size_t)(n + 1) * 256);   // GEMM out f16 [n+1][128]
    char*      bufH     = (char*) alloc((size_t)n * 256);         // H f16; prep scratch alias
    float*     dinv     = (float*)alloc((size_t)n * 4);
    int*       counts   = (int*)  alloc((size_t)n * 4);
    int*       offs     = (int*)  alloc((size_t)(n + 1) * 4);
    int*       localOff = (int*)  alloc((size_t)n * 4);
    int*       btot     = (int*)  alloc((size_t)(nbuck + 1) * 4);
    int*       bktBase  = (int*)  alloc((size_t)(nbuck + 1) * 4);
    int*       tableT   = (int*)  alloc((size_t)(tlen + 1) * 4);
    int*       parts    = (int*)  alloc((size_t)(nseg + 1) * 4);
    int*       er       = (int*)  alloc((size_t)erCap * 4);
    _Float16*  pW       = (_Float16*)alloc(3 * 16384 * 2);
    (void)ws_size; (void)n_in; (void)out_size;

    // bed + brank alias bufH (dead until first aggregate; consumed inside k_prep)
    int2* bed   = (int2*)bufH;                       // e*8 = 12.8 MB
    int*  brank = (int*)(bufH + (size_t)e * 8);      // e*4 = 6.4 MB  (total 19.2 < 25.6 MB)

    PrepArgs pa;
    pa.W1 = W1; pa.W2 = W2; pa.W3 = W3; pa.pW = pW;
    pa.src = src; pa.dst = dst;
    pa.tableT = tableT; pa.parts = parts;
    pa.bed = bed; pa.brank = brank;
    pa.counts = counts; pa.dinv = dinv; pa.localOff = localOff;
    pa.btot = btot; pa.bucketBase = bktBase;
    pa.offs = offs; pa.er = er;
    pa.bufAzero = (unsigned int*)(bufA + (size_t)n * 256);
    pa.nA = nA; pa.nbuck = nbuck; pa.tlen = tlen; pa.nseg = nseg;
    pa.n = n; pa.e = e;

    void* kargs[] = { &pa };
    hipLaunchCooperativeKernel((const void*)k_prep, dim3(PREP_G), dim3(256),
                               kargs, 0, stream);

    int gGemm = (n + 63) / 64;
    int gAgg  = (n + 7) / 8;

    k_gemm_mfma<true><<<gGemm, 256, 0, stream>>>(x, pW, dinv, (uint4*)bufA, n);
    k_aggregate<false><<<gAgg, 256, 0, stream>>>((const uint2*)bufA, offs, er, dinv,
                                                 b1, g1, be1, rm1, rv1, (uint2*)bufH,
                                                 nullptr, nullptr, nullptr, n);

    k_gemm_mfma<false><<<gGemm, 256, 0, stream>>>(bufH, pW + 16384, dinv, (uint4*)bufA, n);
    k_aggregate<false><<<gAgg, 256, 0, stream>>>((const uint2*)bufA, offs, er, dinv,
                                                 b2, g2, be2, rm2, rv2, (uint2*)bufH,
                                                 nullptr, nullptr, nullptr, n);

    k_gemm_mfma<false><<<gGemm, 256, 0, stream>>>(bufH, pW + 32768, dinv, (uint4*)bufA, n);
    k_aggregate<true><<<gAgg, 256, 0, stream>>>((const uint2*)bufA, offs, er, dinv,
                                                b3, g3, be3, rm3, rv3, nullptr,
                                                Wc, bc, out, n);
}